// Round 13
// baseline (407.423 us; speedup 1.0000x reference)
//
#include <hip/hip_runtime.h>
#include <math.h>

#define DD 256
#define KK 8192
#define NN 16384
#define DECAYF 0.99f
#define EPSF 1e-5f
#define TAU 4e-3f

// output layout (floats)
#define O_Q    0
#define O_LOSS 4194304
#define O_PERP 4194305
#define O_IDX  4194306
#define O_EMB  4210690

typedef float f32x4 __attribute__((ext_vector_type(4)));
typedef _Float16 f16x8 __attribute__((ext_vector_type(8)));

__device__ __forceinline__ unsigned short f2h(float f) {
  union { _Float16 h; unsigned short u; } c;
  c.h = (_Float16)f;
  return c.u;
}

__device__ __forceinline__ void gll16(const void* g, void* l) {
  __builtin_amdgcn_global_load_lds((const __attribute__((address_space(1))) void*)g,
                                   (__attribute__((address_space(3))) void*)l, 16, 0, 0);
}

// DPP lane routing (VALU pipe, replaces ds_swizzle-based __shfl_xor).
#define DPPI(x, ctrl) __builtin_amdgcn_update_dpp((x), (x), (ctrl), 0xf, 0xf, true)
#define DPPF(x, ctrl) __int_as_float(__builtin_amdgcn_update_dpp(__float_as_int(x), __float_as_int(x), (ctrl), 0xf, 0xf, true))

// ------- fused convert + all workspace init (no memset nodes) -------
// bx<4096: x->fp16; bx<64 also init keysR; bx 64..95 zero counts;
// bx 96 zeroes loss_part + listc. bx>=4096: emb transpose + esqp partials.
__global__ void k_convert_xe(const float* __restrict__ x, unsigned short* __restrict__ Ah,
                             const float* __restrict__ emb, unsigned short* __restrict__ Eh,
                             float* __restrict__ embT, float* __restrict__ esqp,
                             unsigned long long* __restrict__ keysR,
                             float* __restrict__ counts, float* __restrict__ loss_part,
                             int* __restrict__ listc) {
  __shared__ float ld[32 * 33];
  int bx = blockIdx.x;
  int t = threadIdx.x;
  if (bx < 4096) {
    int i = bx * 256 + t; // float4 index, 1048576 total
    float4 v = ((const float4*)x)[i];
    ushort4 h;
    h.x = f2h(v.x); h.y = f2h(v.y); h.z = f2h(v.z); h.w = f2h(v.w);
    ((ushort4*)Ah)[i] = h;
    if (bx < 64) {
      keysR[bx * 256 + t] = ~0ull;
    } else if (bx < 96) {
      counts[(bx - 64) * 256 + t] = 0.f;
    } else if (bx == 96) {
      loss_part[t] = 0.f;
      if (t == 0) *listc = 0;
    }
    return;
  }
  int eb = bx - 4096;
  int k0 = (eb & 255) * 32, d0b = eb >> 8; // d0b in [0,8)
  {
    int din = t >> 3, kq = (t & 7) * 4;
    float4 v = *(const float4*)(emb + (size_t)(d0b * 32 + din) * KK + k0 + kq);
    ld[din * 33 + kq + 0] = v.x; ld[din * 33 + kq + 1] = v.y;
    ld[din * 33 + kq + 2] = v.z; ld[din * 33 + kq + 3] = v.w;
  }
  __syncthreads();
  int kout = t >> 3, dq = (t & 7) * 4;
  float f0 = ld[(dq + 0) * 33 + kout], f1 = ld[(dq + 1) * 33 + kout];
  float f2 = ld[(dq + 2) * 33 + kout], f3 = ld[(dq + 3) * 33 + kout];
  size_t o = (size_t)(k0 + kout) * DD + d0b * 32 + dq;
  float4 fv; fv.x = f0; fv.y = f1; fv.z = f2; fv.w = f3;
  *(float4*)(embT + o) = fv;
  ushort4 hv;
  hv.x = f2h(f0); hv.y = f2h(f1); hv.z = f2h(f2); hv.w = f2h(f3);
  *(ushort4*)(Eh + o) = hv;
  // esq partial: 8 threads (t&7) share kout; overwrite store (no init needed)
  float p = (f0 * f0 + f1 * f1) + (f2 * f2 + f3 * f3);
  p += __shfl_xor(p, 1, 64);
  p += __shfl_xor(p, 2, 64);
  p += __shfl_xor(p, 4, 64);
  if ((t & 7) == 0) esqp[(size_t)(k0 + kout) * 8 + d0b] = p;
}

// ---------------- MFMA distance screening (fp16 single GEMM) ----------------
// grid (64 kb, 128 nb); 4 waves in 2x2; wave tile 64x64 (acc[4][4]).
// Each wave reads only its 64-col half of sB -> 8 ds_read_b128/wave/it
// (half of R12). A direct-to-reg, 4 row-frags, reloaded per kk (WAR-stalled,
// hidden by co-resident blocks). Col-half partials merged via LDS, then one
// coalesced 128-row store per block ([kb][row] layout unchanged).
__launch_bounds__(256, 2)
__global__ void k_dist_mfma(const unsigned short* __restrict__ Ah, const unsigned short* __restrict__ Bh,
                            const float* __restrict__ esqp,
                            float* __restrict__ part1, float* __restrict__ part2,
                            int* __restrict__ partidx) {
  __shared__ __align__(16) unsigned short sB[8192]; // 128 rows x 64 f16 (16 KB)
  __shared__ float sEq[128];
  __shared__ float sP1[256], sP2[256];
  __shared__ int   sPi[256];

  const int tid = threadIdx.x;
  const int w = tid >> 6, lane = tid & 63;
  const int wr = w >> 1, wc = w & 1;
  const int kb = blockIdx.x, nb = blockIdx.y;
  const int row0 = nb * 128, col0 = kb * 128;
  const int m = lane & 15, q = lane >> 4;

  // B staging: call s covers rows (w*4+s)*8 + (lane>>3); chunk (lane&7)^(r&7)
  size_t gB[4];
  int lbB[4];
  #pragma unroll
  for (int s = 0; s < 4; ++s) {
    int g = w * 4 + s;
    int r = g * 8 + (lane >> 3);
    int c = (lane & 7) ^ (r & 7);
    gB[s] = (size_t)(col0 + r) * DD + c * 8;
    lbB[s] = g * 512;
  }

  // A direct: lane (m,q), row-frag i: A[wr*64 + i*16 + m][(kk*4+q)*8 ..+8]
  const unsigned short* pA = Ah + (size_t)(row0 + wr * 64 + m) * DD + q * 8;

  f32x4 acc[4][4];
  #pragma unroll
  for (int i = 0; i < 4; ++i)
    #pragma unroll
    for (int j = 0; j < 4; ++j) acc[i][j] = (f32x4)0.f;

  for (int it = 0; it < 4; ++it) {
    const int d0 = it * 64;
    __syncthreads();
    #pragma unroll
    for (int s = 0; s < 4; ++s) gll16(Bh + gB[s] + d0, sB + lbB[s]);
    f16x8 a[4];
    #pragma unroll
    for (int i = 0; i < 4; ++i) a[i] = *(const f16x8*)(pA + i * 16 * DD + d0);
    __syncthreads();
    #pragma unroll
    for (int kk = 0; kk < 2; ++kk) {
      if (kk == 1) {
        #pragma unroll
        for (int i = 0; i < 4; ++i) a[i] = *(const f16x8*)(pA + i * 16 * DD + d0 + 32);
      }
      #pragma unroll
      for (int j = 0; j < 4; ++j) {
        int cn = wc * 64 + j * 16 + m;
        int slot = (kk * 4 + q) ^ (cn & 7);
        f16x8 b = *(const f16x8*)(sB + cn * 64 + slot * 8);
        #pragma unroll
        for (int i = 0; i < 4; ++i)
          acc[i][j] = __builtin_amdgcn_mfma_f32_16x16x32_f16(a[i], b, acc[i][j], 0, 0, 0);
      }
    }
  }

  // esq pre-reduce (EPILOGUE): thread t sums half (t&1) of col (t>>1); 4KB coalesced
  {
    int col = tid >> 1, half = tid & 1;
    const float4* ep = (const float4*)esqp + (size_t)(col0 + col) * 2 + half;
    float4 s = *ep;
    float p = (s.x + s.y) + (s.z + s.w);
    p += __shfl_xor(p, 1, 64); // partner lane, same col
    if (half == 0) sEq[col] = p;
  }
  __syncthreads();

  float eq[4];
  #pragma unroll
  for (int j = 0; j < 4; ++j) eq[j] = sEq[wc * 64 + j * 16 + m];

  // argmin + 2nd-min per col-half; no index tie-break (ties -> TAU -> rescore)
  #define RSTAGE(CTRL) {                                  \
    float ov = DPPF(m1, CTRL);                            \
    int   oi = DPPI(bi, CTRL);                            \
    float o2 = DPPF(m2, CTRL);                            \
    m2 = fminf(fminf(m2, o2), fmaxf(m1, ov));             \
    bool p = ov < m1;                                     \
    m1 = fminf(m1, ov);                                   \
    bi = p ? oi : bi;                                     \
  }
  #pragma unroll
  for (int i = 0; i < 4; ++i) {
    #pragma unroll
    for (int reg = 0; reg < 4; ++reg) {
      float m1 = 3.402823466e+38f, m2 = 3.402823466e+38f;
      int bi = 0;
      #pragma unroll
      for (int j = 0; j < 4; ++j) {
        float dd = fmaf(-2.0f, acc[i][j][reg], eq[j]);
        bool p = dd < m1;
        m2 = fminf(m2, fmaxf(dd, m1));
        m1 = fminf(m1, dd);
        bi = p ? (col0 + wc * 64 + j * 16 + m) : bi;
      }
      RSTAGE(0xB1)   // xor1  (quad_perm 1,0,3,2)
      RSTAGE(0x4E)   // xor2  (quad_perm 2,3,0,1)
      RSTAGE(0x141)  // xor7  (row_half_mirror)
      RSTAGE(0x140)  // xor15 (row_mirror)
      if (m == 0) {
        int r = wr * 64 + i * 16 + q * 4 + reg; // 0..127 within block
        sP1[wc * 128 + r] = m1;
        sP2[wc * 128 + r] = m2;
        sPi[wc * 128 + r] = bi;
      }
    }
  }
  #undef RSTAGE
  __syncthreads();
  // merge the two col-halves; one coalesced 128-row store per block
  if (tid < 128) {
    float a1 = sP1[tid],       a2 = sP2[tid];
    float b1 = sP1[128 + tid], b2 = sP2[128 + tid];
    float mm1 = fminf(a1, b1);
    float mm2 = fminf(fminf(a2, b2), fmaxf(a1, b1));
    int ii = (b1 < a1) ? sPi[128 + tid] : sPi[tid];
    int pidx = kb * NN + row0 + tid;  // [kb][row]
    part1[pidx] = mm1; part2[pidx] = mm2; partidx[pidx] = ii;
  }
}

// -------- per-row 2-min merge over 64 kb partials ([kb][row] layout) -------
// grid 128 x 128: thread owns one row; coalesced loads, no shuffles.
// Zeroes dwT (=part1/part2 alias) element-by-element after read.
__global__ void k_argmin2(float* __restrict__ part1, float* __restrict__ part2,
                          const int* __restrict__ partidx, int* __restrict__ idxw,
                          int* __restrict__ listc, int* __restrict__ list) {
  int row = blockIdx.x * 128 + threadIdx.x;
  float m1 = 3.402823466e+38f, m2 = 3.402823466e+38f;
  int bi = 0;
  for (int kb = 0; kb < 64; ++kb) {
    int f = kb * NN + row;
    float a1 = part1[f], a2 = part2[f];
    int ai = partidx[f];
    part1[f] = 0.f;  // dwT alias zeroing (own element only)
    part2[f] = 0.f;
    m2 = fminf(fminf(m2, a2), fmaxf(m1, a1));
    bool p = a1 < m1;
    m1 = fminf(m1, a1);
    bi = p ? ai : bi;
  }
  idxw[row] = bi;
  if (m2 - m1 < TAU) { int pos = atomicAdd(listc, 1); list[pos] = row; }
}

// ---------------- fp64 rescore of near-tie rows (parallel over rows) --------
// grid (256 k-slices, 8 row-stripes); early-exit BEFORE staging when empty.
__global__ void k_rescore(const float* __restrict__ x, const float* __restrict__ emb,
                          const int* __restrict__ listc, const int* __restrict__ list,
                          unsigned long long* __restrict__ keysR) {
  __shared__ float se[8192];
  __shared__ double red[256];
  const int t = threadIdx.x;
  const int k0 = blockIdx.x * 32;
  int cnt = *listc;
  if ((int)blockIdx.y >= cnt) return; // covers cnt==0; saves 32KB staging/block
  #pragma unroll
  for (int i = 0; i < 32; ++i) {
    int elem = i * 256 + t;
    int d = elem >> 5, c = elem & 31;
    se[d * 32 + c] = emb[(size_t)d * KK + k0 + c];
  }
  __syncthreads();
  const int c = t & 31, p = t >> 5;
  for (int li = blockIdx.y; li < cnt; li += gridDim.y) {
    int row = list[li];
    const float* xr = x + (size_t)row * DD;
    double acc = 0.0;
    #pragma unroll
    for (int j = 0; j < 32; ++j) {
      int d = p * 32 + j;
      double df = (double)xr[d] - (double)se[d * 32 + c];
      acc = fma(df, df, acc);
    }
    red[c * 8 + p] = acc;
    __syncthreads();
    if (t < 64) {
      unsigned long long key = ~0ull;
      if (t < 32) {
        double dist = 0.0;
        #pragma unroll
        for (int qq = 0; qq < 8; ++qq) dist += red[t * 8 + qq];
        key = ((unsigned long long)__double_as_longlong(dist) & ~0x1FFFull)
              | (unsigned long long)(k0 + t);
      }
      #pragma unroll
      for (int s = 1; s < 64; s <<= 1) {
        unsigned long long o = __shfl_xor(key, s, 64);
        if (o < key) key = o;
      }
      if (t == 0) atomicMin(&keysR[row], key);
    }
    __syncthreads();
  }
}

// ---------------- gather + outputs + scatter stats ----------------
__global__ void k_gather(const float* __restrict__ x, const float* __restrict__ embT,
                         const int* __restrict__ idxw, const unsigned long long* __restrict__ keysR,
                         const int* __restrict__ train,
                         float* __restrict__ outq, float* __restrict__ outidx,
                         float* __restrict__ dwT, float* __restrict__ counts,
                         float* __restrict__ loss_part) {
  int w = threadIdx.x >> 6, l = threadIdx.x & 63;
  int n = blockIdx.x * 4 + w;
  unsigned long long kv = keysR[n];
  int k = (kv != ~0ull) ? (int)(kv & 0x1FFFull) : idxw[n];
  float4 xv = ((const float4*)(x + (size_t)n * DD))[l];
  float4 qv = ((const float4*)(embT + (size_t)k * DD))[l];
  int d = l * 4;

  ((float4*)(outq + (size_t)n * DD))[l] = qv; // x + (q - x) == q

  float e0 = qv.x - xv.x, e1 = qv.y - xv.y, e2 = qv.z - xv.z, e3 = qv.w - xv.w;
  float ls = (e0 * e0 + e1 * e1) + (e2 * e2 + e3 * e3);

  if (*train) {
    const float wdw = 1.0f - DECAYF;
    float* base = dwT + (size_t)k * DD + d;
    atomicAdd(base + 0, xv.x * wdw);
    atomicAdd(base + 1, xv.y * wdw);
    atomicAdd(base + 2, xv.z * wdw);
    atomicAdd(base + 3, xv.w * wdw);
  }

  #pragma unroll
  for (int s = 1; s < 64; s <<= 1) ls += __shfl_xor(ls, s, 64);
  if (l == 0) {
    atomicAdd(&loss_part[blockIdx.x & 255], ls);
    atomicAdd(&counts[k], 1.0f);
    outidx[n] = (float)k;
  }
}

// ------- finalize: per-block nsum/csn (k_stats folded in) + EMA + out4 ------
// block (0,0) additionally computes loss + perplexity.
__global__ void k_final(const float* __restrict__ dwT, const float* __restrict__ ema_dw,
                        const float* __restrict__ emb, const float* __restrict__ counts,
                        const float* __restrict__ ema_cs, const float* __restrict__ loss_part,
                        const int* __restrict__ counter, const int* __restrict__ train,
                        float* __restrict__ out4, float* __restrict__ outloss,
                        float* __restrict__ outperp) {
  __shared__ float ld[32 * 33];
  __shared__ float s_red[4], s_l[4], s_e[4];
  __shared__ float csn_s[32];
  int t = threadIdx.x;
  int k0 = blockIdx.x * 32, d0 = blockIdx.y * 32;
  int w = t >> 6, lane = t & 63;

  if (blockIdx.x == 0 && blockIdx.y == 0) {
    float lloc = loss_part[t];
    float eloc = 0.f;
    for (int i = 0; i < 32; ++i) {
      float cc = counts[t + i * 256];
      float pp = cc * (1.0f / 16384.0f);
      eloc += pp * logf(pp + 1e-10f);
    }
    #pragma unroll
    for (int s = 1; s < 64; s <<= 1) {
      lloc += __shfl_xor(lloc, s, 64);
      eloc += __shfl_xor(eloc, s, 64);
    }
    if (lane == 0) { s_l[w] = lloc; s_e[w] = eloc; }
    __syncthreads();
    if (t == 0) {
      outloss[0] = 0.25f * (((s_l[0] + s_l[1]) + (s_l[2] + s_l[3])) / 4194304.0f);
      outperp[0] = expf(-((s_e[0] + s_e[1]) + (s_e[2] + s_e[3])));
    }
  }

  if (*train) {
    float debias = 1.0f - powf(DECAYF, (float)(*counter + 1));
    float inv = 1.0f / debias;
    float nloc = 0.f;
    for (int i = 0; i < 32; ++i) {
      int k = t + i * 256;
      nloc += fmaf(counts[k], 1.0f - DECAYF, ema_cs[k] * DECAYF);
    }
    #pragma unroll
    for (int s = 1; s < 64; s <<= 1) nloc += __shfl_xor(nloc, s, 64);
    if (lane == 0) s_red[w] = nloc;
    __syncthreads();
    float nsum = ((s_red[0] + s_red[1]) + (s_red[2] + s_red[3])) * inv;
    if (t < 32) {
      int k = k0 + t;
      float a = fmaf(counts[k], 1.0f - DECAYF, ema_cs[k] * DECAYF) * inv;
      csn_s[t] = (a + EPSF) / (nsum + 8192.0f * EPSF) * nsum;
    }
    {
      int ki = t >> 3, dq = (t & 7) * 4;
      float4 v = *(const float4*)(dwT + (size_t)(k0 + ki) * DD + d0 + dq);
      ld[ki * 33 + dq + 0] = v.x; ld[ki * 33 + dq + 1] = v.y;
      ld[ki * 33 + dq + 2] = v.z; ld[ki * 33 + dq + 3] = v.w;
    }
    __syncthreads();
    int dout = t >> 3, kq = (t & 7) * 4;
    size_t o = (size_t)(d0 + dout) * KK + k0 + kq;
    float4 e = *(const float4*)(ema_dw + o);
    float4 r;
    r.x = fmaf(e.x, DECAYF, ld[(kq + 0) * 33 + dout]) * inv / csn_s[kq + 0];
    r.y = fmaf(e.y, DECAYF, ld[(kq + 1) * 33 + dout]) * inv / csn_s[kq + 1];
    r.z = fmaf(e.z, DECAYF, ld[(kq + 2) * 33 + dout]) * inv / csn_s[kq + 2];
    r.w = fmaf(e.w, DECAYF, ld[(kq + 3) * 33 + dout]) * inv / csn_s[kq + 3];
    *(float4*)(out4 + o) = r;
  } else {
    int dout = t >> 3, kq = (t & 7) * 4;
    size_t o = (size_t)(d0 + dout) * KK + k0 + kq;
    *(float4*)(out4 + o) = *(const float4*)(emb + o);
  }
}

extern "C" void kernel_launch(void* const* d_in, const int* in_sizes, int n_in,
                              void* d_out, int out_size, void* d_ws, size_t ws_size,
                              hipStream_t stream) {
  (void)in_sizes; (void)n_in; (void)out_size; (void)ws_size;
  const float* x      = (const float*)d_in[0];
  const float* emb    = (const float*)d_in[1];
  const float* ema_cs = (const float*)d_in[2];
  const float* ema_dw = (const float*)d_in[3];
  const int*   counter = (const int*)d_in[4];
  const int*   train   = (const int*)d_in[5];

  float* out = (float*)d_out;
  float* outq    = out + O_Q;
  float* outloss = out + O_LOSS;
  float* outperp = out + O_PERP;
  float* outidx  = out + O_IDX;
  float* out4    = out + O_EMB;

  // workspace carve (bytes)
  char* W = (char*)d_ws;
  unsigned short* Ah   = (unsigned short*)(W);              //  8 MB fp16 x
  unsigned short* Eh   = (unsigned short*)(W + 8388608);    //  4 MB fp16 embT
  float* embT          = (float*)(W + 12582912);            //  8 MB fp32 embT
  float* part1         = (float*)(W + 20971520);            //  4 MB [kb][row]
  float* part2         = (float*)(W + 25165824);            //  4 MB [kb][row]
  int*   partidx       = (int*)(W + 29360128);              //  4 MB [kb][row]
  float* dwT           = part1;                             //  8 MB alias (dead after argmin2)
  unsigned long long* keysR = (unsigned long long*)(W + 33554432); // 128 KB
  float* esqp          = (float*)(W + 33685504);            // 256 KB [k*8+b]
  float* counts        = (float*)(W + 33947648);            // 32 KB
  float* loss_part     = (float*)(W + 33980416);            // 1 KB
  int*   listc         = (int*)(W + 33981440);              // 4 B
  int*   list          = (int*)(W + 33981444);              // 64 KB
  int*   idxw          = (int*)(W + 34046980);              // 64 KB

  // no memsets: all init fused into k_convert_xe
  k_convert_xe<<<6144, 256, 0, stream>>>(x, Ah, emb, Eh, embT, esqp, keysR, counts, loss_part, listc);
  k_dist_mfma<<<dim3(64, 128), 256, 0, stream>>>(Ah, Eh, esqp, part1, part2, partidx);
  k_argmin2<<<128, 128, 0, stream>>>(part1, part2, partidx, idxw, listc, list);
  k_rescore<<<dim3(256, 8), 256, 0, stream>>>(x, emb, listc, list, keysR);
  k_gather<<<4096, 256, 0, stream>>>(x, embT, idxw, keysR, train, outq, outidx, dwT, counts, loss_part);
  k_final<<<dim3(256, 8), 256, 0, stream>>>(dwT, ema_dw, emb, counts, ema_cs, loss_part, counter, train, out4, outloss, outperp);
}

// Round 14
// 352.201 us; speedup vs baseline: 1.1568x; 1.1568x over previous
//
#include <hip/hip_runtime.h>
#include <math.h>

#define DD 256
#define KK 8192
#define NN 16384
#define DECAYF 0.99f
#define EPSF 1e-5f
#define TAU 4e-3f

// output layout (floats)
#define O_Q    0
#define O_LOSS 4194304
#define O_PERP 4194305
#define O_IDX  4194306
#define O_EMB  4210690

typedef float f32x4 __attribute__((ext_vector_type(4)));
typedef _Float16 f16x8 __attribute__((ext_vector_type(8)));

__device__ __forceinline__ unsigned short f2h(float f) {
  union { _Float16 h; unsigned short u; } c;
  c.h = (_Float16)f;
  return c.u;
}

__device__ __forceinline__ void gll16(const void* g, void* l) {
  __builtin_amdgcn_global_load_lds((const __attribute__((address_space(1))) void*)g,
                                   (__attribute__((address_space(3))) void*)l, 16, 0, 0);
}

// DPP lane routing (VALU pipe, replaces ds_swizzle-based __shfl_xor).
#define DPPI(x, ctrl) __builtin_amdgcn_update_dpp((x), (x), (ctrl), 0xf, 0xf, true)
#define DPPF(x, ctrl) __int_as_float(__builtin_amdgcn_update_dpp(__float_as_int(x), __float_as_int(x), (ctrl), 0xf, 0xf, true))

// ------- fused convert + all workspace init (no memset nodes) -------
// bx<4096: x->fp16; bx<64 also init keysR; bx 64..95 zero counts;
// bx 96 zeroes loss_part + listc. bx>=4096: emb transpose + esqp partials.
__global__ void k_convert_xe(const float* __restrict__ x, unsigned short* __restrict__ Ah,
                             const float* __restrict__ emb, unsigned short* __restrict__ Eh,
                             float* __restrict__ embT, float* __restrict__ esqp,
                             unsigned long long* __restrict__ keysR,
                             float* __restrict__ counts, float* __restrict__ loss_part,
                             int* __restrict__ listc) {
  __shared__ float ld[32 * 33];
  int bx = blockIdx.x;
  int t = threadIdx.x;
  if (bx < 4096) {
    int i = bx * 256 + t; // float4 index, 1048576 total
    float4 v = ((const float4*)x)[i];
    ushort4 h;
    h.x = f2h(v.x); h.y = f2h(v.y); h.z = f2h(v.z); h.w = f2h(v.w);
    ((ushort4*)Ah)[i] = h;
    if (bx < 64) {
      keysR[bx * 256 + t] = ~0ull;
    } else if (bx < 96) {
      counts[(bx - 64) * 256 + t] = 0.f;
    } else if (bx == 96) {
      loss_part[t] = 0.f;
      if (t == 0) *listc = 0;
    }
    return;
  }
  int eb = bx - 4096;
  int k0 = (eb & 255) * 32, d0b = eb >> 8; // d0b in [0,8)
  {
    int din = t >> 3, kq = (t & 7) * 4;
    float4 v = *(const float4*)(emb + (size_t)(d0b * 32 + din) * KK + k0 + kq);
    ld[din * 33 + kq + 0] = v.x; ld[din * 33 + kq + 1] = v.y;
    ld[din * 33 + kq + 2] = v.z; ld[din * 33 + kq + 3] = v.w;
  }
  __syncthreads();
  int kout = t >> 3, dq = (t & 7) * 4;
  float f0 = ld[(dq + 0) * 33 + kout], f1 = ld[(dq + 1) * 33 + kout];
  float f2 = ld[(dq + 2) * 33 + kout], f3 = ld[(dq + 3) * 33 + kout];
  size_t o = (size_t)(k0 + kout) * DD + d0b * 32 + dq;
  float4 fv; fv.x = f0; fv.y = f1; fv.z = f2; fv.w = f3;
  *(float4*)(embT + o) = fv;
  ushort4 hv;
  hv.x = f2h(f0); hv.y = f2h(f1); hv.z = f2h(f2); hv.w = f2h(f3);
  *(ushort4*)(Eh + o) = hv;
  // esq partial: 8 threads (t&7) share kout; overwrite store (no init needed)
  float p = (f0 * f0 + f1 * f1) + (f2 * f2 + f3 * f3);
  p += __shfl_xor(p, 1, 64);
  p += __shfl_xor(p, 2, 64);
  p += __shfl_xor(p, 4, 64);
  if ((t & 7) == 0) esqp[(size_t)(k0 + kout) * 8 + d0b] = p;
}

// ---------------- MFMA distance screening (fp16 single GEMM) ----------------
// grid (64 kb, 128 nb); 4 waves; tile 128x128; A direct-to-reg, B via LDS.
// sEq pre-reduce in EPILOGUE (keeps main-loop VGPR at ~60).
// Partials stored [kb][row]: wave's 32 rows contiguous -> no write-amp.
__launch_bounds__(256, 2)
__global__ void k_dist_mfma(const unsigned short* __restrict__ Ah, const unsigned short* __restrict__ Bh,
                            const float* __restrict__ esqp,
                            float* __restrict__ part1, float* __restrict__ part2,
                            int* __restrict__ partidx) {
  __shared__ __align__(16) unsigned short sB[8192]; // 128 rows x 64 f16 (16 KB)
  __shared__ float sEq[128];

  const int tid = threadIdx.x;
  const int w = tid >> 6, lane = tid & 63;
  const int kb = blockIdx.x, nb = blockIdx.y;
  const int row0 = nb * 128, col0 = kb * 128;
  const int m = lane & 15, q = lane >> 4;

  // B staging: call s covers rows (w*4+s)*8 + (lane>>3); chunk (lane&7)^(r&7)
  size_t gB[4];
  int lbB[4];
  #pragma unroll
  for (int s = 0; s < 4; ++s) {
    int g = w * 4 + s;
    int r = g * 8 + (lane >> 3);
    int c = (lane & 7) ^ (r & 7);
    gB[s] = (size_t)(col0 + r) * DD + c * 8;
    lbB[s] = g * 512;
  }

  // A direct: lane (m,q) holds A[w*32 + i*16 + m][(kk*4+q)*8 ..+8] at d0=it*64
  const unsigned short* pA0 = Ah + (size_t)(row0 + w * 32 + m) * DD + q * 8;
  const unsigned short* pA1 = pA0 + 16 * DD;

  f32x4 acc[2][8];
  #pragma unroll
  for (int i = 0; i < 2; ++i)
    #pragma unroll
    for (int j = 0; j < 8; ++j) acc[i][j] = (f32x4)0.f;

  for (int it = 0; it < 4; ++it) {
    const int d0 = it * 64;
    __syncthreads();
    #pragma unroll
    for (int s = 0; s < 4; ++s) gll16(Bh + gB[s] + d0, sB + lbB[s]);
    f16x8 a[2][2];
    #pragma unroll
    for (int kk = 0; kk < 2; ++kk) {
      a[kk][0] = *(const f16x8*)(pA0 + d0 + kk * 32);
      a[kk][1] = *(const f16x8*)(pA1 + d0 + kk * 32);
    }
    __syncthreads();
    #pragma unroll
    for (int kk = 0; kk < 2; ++kk) {
      #pragma unroll
      for (int j = 0; j < 8; ++j) {
        int cn = j * 16 + m;
        int slot = (kk * 4 + q) ^ (cn & 7);
        f16x8 b = *(const f16x8*)(sB + cn * 64 + slot * 8);
        acc[0][j] = __builtin_amdgcn_mfma_f32_16x16x32_f16(a[kk][0], b, acc[0][j], 0, 0, 0);
        acc[1][j] = __builtin_amdgcn_mfma_f32_16x16x32_f16(a[kk][1], b, acc[1][j], 0, 0, 0);
      }
    }
  }

  // esq pre-reduce (EPILOGUE): thread t sums half (t&1) of col (t>>1); 4KB coalesced
  {
    int col = tid >> 1, half = tid & 1;
    const float4* ep = (const float4*)esqp + (size_t)(col0 + col) * 2 + half;
    float4 s = *ep;
    float p = (s.x + s.y) + (s.z + s.w);
    p += __shfl_xor(p, 1, 64); // partner lane, same col
    if (half == 0) sEq[col] = p;
  }
  __syncthreads();

  float eq[8];
  #pragma unroll
  for (int j = 0; j < 8; ++j) eq[j] = sEq[j * 16 + m];

  // argmin + 2nd-min; no index tie-break (exact ties -> gap 0 < TAU -> rescore)
  #define RSTAGE(CTRL) {                                  \
    float ov = DPPF(m1, CTRL);                            \
    int   oi = DPPI(bi, CTRL);                            \
    float o2 = DPPF(m2, CTRL);                            \
    m2 = fminf(fminf(m2, o2), fmaxf(m1, ov));             \
    bool p = ov < m1;                                     \
    m1 = fminf(m1, ov);                                   \
    bi = p ? oi : bi;                                     \
  }
  #pragma unroll
  for (int i = 0; i < 2; ++i) {
    #pragma unroll
    for (int reg = 0; reg < 4; ++reg) {
      float m1 = 3.402823466e+38f, m2 = 3.402823466e+38f;
      int bi = 0;
      #pragma unroll
      for (int j = 0; j < 8; ++j) {
        float dd = fmaf(-2.0f, acc[i][j][reg], eq[j]);
        bool p = dd < m1;
        m2 = fminf(m2, fmaxf(dd, m1));
        m1 = fminf(m1, dd);
        bi = p ? (col0 + j * 16 + m) : bi;
      }
      RSTAGE(0xB1)   // xor1  (quad_perm 1,0,3,2)
      RSTAGE(0x4E)   // xor2  (quad_perm 2,3,0,1)
      RSTAGE(0x141)  // xor7  (row_half_mirror)
      RSTAGE(0x140)  // xor15 (row_mirror)
      if (m == 0) {
        int prow = row0 + w * 32 + i * 16 + q * 4 + reg;
        int pidx = kb * NN + prow;  // [kb][row]: wave's 32 rows contiguous
        part1[pidx] = m1; part2[pidx] = m2; partidx[pidx] = bi;
      }
    }
  }
  #undef RSTAGE
}

// -------- per-row 2-min merge over 64 kb partials ([kb][row] layout) -------
// grid 64 x 256: thread owns one row; 64 coalesced loads per array, no
// shuffles. Zeroes dwT (=part1/part2 alias) element-by-element after read
// (same-thread read-then-zero: race-free across blocks).
__global__ void k_argmin2(float* __restrict__ part1, float* __restrict__ part2,
                          const int* __restrict__ partidx, int* __restrict__ idxw,
                          int* __restrict__ listc, int* __restrict__ list) {
  int row = blockIdx.x * 256 + threadIdx.x;
  float m1 = 3.402823466e+38f, m2 = 3.402823466e+38f;
  int bi = 0;
  for (int kb = 0; kb < 64; ++kb) {
    int f = kb * NN + row;
    float a1 = part1[f], a2 = part2[f];
    int ai = partidx[f];
    part1[f] = 0.f;  // dwT alias zeroing (own element only)
    part2[f] = 0.f;
    m2 = fminf(fminf(m2, a2), fmaxf(m1, a1));
    bool p = a1 < m1;
    m1 = fminf(m1, a1);
    bi = p ? ai : bi;
  }
  idxw[row] = bi;
  if (m2 - m1 < TAU) { int pos = atomicAdd(listc, 1); list[pos] = row; }
}

// ---------------- fp64 rescore of near-tie rows (parallel over rows) --------
// grid (256 k-slices, 8 row-stripes); early-exit BEFORE staging when empty.
__global__ void k_rescore(const float* __restrict__ x, const float* __restrict__ emb,
                          const int* __restrict__ listc, const int* __restrict__ list,
                          unsigned long long* __restrict__ keysR) {
  __shared__ float se[8192];
  __shared__ double red[256];
  const int t = threadIdx.x;
  const int k0 = blockIdx.x * 32;
  int cnt = *listc;
  if ((int)blockIdx.y >= cnt) return; // covers cnt==0; saves 32KB staging/block
  #pragma unroll
  for (int i = 0; i < 32; ++i) {
    int elem = i * 256 + t;
    int d = elem >> 5, c = elem & 31;
    se[d * 32 + c] = emb[(size_t)d * KK + k0 + c];
  }
  __syncthreads();
  const int c = t & 31, p = t >> 5;
  for (int li = blockIdx.y; li < cnt; li += gridDim.y) {
    int row = list[li];
    const float* xr = x + (size_t)row * DD;
    double acc = 0.0;
    #pragma unroll
    for (int j = 0; j < 32; ++j) {
      int d = p * 32 + j;
      double df = (double)xr[d] - (double)se[d * 32 + c];
      acc = fma(df, df, acc);
    }
    red[c * 8 + p] = acc;
    __syncthreads();
    if (t < 64) {
      unsigned long long key = ~0ull;
      if (t < 32) {
        double dist = 0.0;
        #pragma unroll
        for (int qq = 0; qq < 8; ++qq) dist += red[t * 8 + qq];
        key = ((unsigned long long)__double_as_longlong(dist) & ~0x1FFFull)
              | (unsigned long long)(k0 + t);
      }
      #pragma unroll
      for (int s = 1; s < 64; s <<= 1) {
        unsigned long long o = __shfl_xor(key, s, 64);
        if (o < key) key = o;
      }
      if (t == 0) atomicMin(&keysR[row], key);
    }
    __syncthreads();
  }
}

// ---------------- gather + outputs + scatter stats ----------------
__global__ void k_gather(const float* __restrict__ x, const float* __restrict__ embT,
                         const int* __restrict__ idxw, const unsigned long long* __restrict__ keysR,
                         const int* __restrict__ train,
                         float* __restrict__ outq, float* __restrict__ outidx,
                         float* __restrict__ dwT, float* __restrict__ counts,
                         float* __restrict__ loss_part) {
  int w = threadIdx.x >> 6, l = threadIdx.x & 63;
  int n = blockIdx.x * 4 + w;
  unsigned long long kv = keysR[n];
  int k = (kv != ~0ull) ? (int)(kv & 0x1FFFull) : idxw[n];
  float4 xv = ((const float4*)(x + (size_t)n * DD))[l];
  float4 qv = ((const float4*)(embT + (size_t)k * DD))[l];
  int d = l * 4;

  ((float4*)(outq + (size_t)n * DD))[l] = qv; // x + (q - x) == q

  float e0 = qv.x - xv.x, e1 = qv.y - xv.y, e2 = qv.z - xv.z, e3 = qv.w - xv.w;
  float ls = (e0 * e0 + e1 * e1) + (e2 * e2 + e3 * e3);

  if (*train) {
    const float wdw = 1.0f - DECAYF;
    float* base = dwT + (size_t)k * DD + d;
    atomicAdd(base + 0, xv.x * wdw);
    atomicAdd(base + 1, xv.y * wdw);
    atomicAdd(base + 2, xv.z * wdw);
    atomicAdd(base + 3, xv.w * wdw);
  }

  #pragma unroll
  for (int s = 1; s < 64; s <<= 1) ls += __shfl_xor(ls, s, 64);
  if (l == 0) {
    atomicAdd(&loss_part[blockIdx.x & 255], ls);
    atomicAdd(&counts[k], 1.0f);
    outidx[n] = (float)k;
  }
}

// ------- finalize: per-block nsum/csn (k_stats folded in) + EMA + out4 ------
// block (0,0) additionally computes loss + perplexity.
__global__ void k_final(const float* __restrict__ dwT, const float* __restrict__ ema_dw,
                        const float* __restrict__ emb, const float* __restrict__ counts,
                        const float* __restrict__ ema_cs, const float* __restrict__ loss_part,
                        const int* __restrict__ counter, const int* __restrict__ train,
                        float* __restrict__ out4, float* __restrict__ outloss,
                        float* __restrict__ outperp) {
  __shared__ float ld[32 * 33];
  __shared__ float s_red[4], s_l[4], s_e[4];
  __shared__ float csn_s[32];
  int t = threadIdx.x;
  int k0 = blockIdx.x * 32, d0 = blockIdx.y * 32;
  int w = t >> 6, lane = t & 63;

  if (blockIdx.x == 0 && blockIdx.y == 0) {
    float lloc = loss_part[t];
    float eloc = 0.f;
    for (int i = 0; i < 32; ++i) {
      float cc = counts[t + i * 256];
      float pp = cc * (1.0f / 16384.0f);
      eloc += pp * logf(pp + 1e-10f);
    }
    #pragma unroll
    for (int s = 1; s < 64; s <<= 1) {
      lloc += __shfl_xor(lloc, s, 64);
      eloc += __shfl_xor(eloc, s, 64);
    }
    if (lane == 0) { s_l[w] = lloc; s_e[w] = eloc; }
    __syncthreads();
    if (t == 0) {
      outloss[0] = 0.25f * (((s_l[0] + s_l[1]) + (s_l[2] + s_l[3])) / 4194304.0f);
      outperp[0] = expf(-((s_e[0] + s_e[1]) + (s_e[2] + s_e[3])));
    }
  }

  if (*train) {
    float debias = 1.0f - powf(DECAYF, (float)(*counter + 1));
    float inv = 1.0f / debias;
    float nloc = 0.f;
    for (int i = 0; i < 32; ++i) {
      int k = t + i * 256;
      nloc += fmaf(counts[k], 1.0f - DECAYF, ema_cs[k] * DECAYF);
    }
    #pragma unroll
    for (int s = 1; s < 64; s <<= 1) nloc += __shfl_xor(nloc, s, 64);
    if (lane == 0) s_red[w] = nloc;
    __syncthreads();
    float nsum = ((s_red[0] + s_red[1]) + (s_red[2] + s_red[3])) * inv;
    if (t < 32) {
      int k = k0 + t;
      float a = fmaf(counts[k], 1.0f - DECAYF, ema_cs[k] * DECAYF) * inv;
      csn_s[t] = (a + EPSF) / (nsum + 8192.0f * EPSF) * nsum;
    }
    {
      int ki = t >> 3, dq = (t & 7) * 4;
      float4 v = *(const float4*)(dwT + (size_t)(k0 + ki) * DD + d0 + dq);
      ld[ki * 33 + dq + 0] = v.x; ld[ki * 33 + dq + 1] = v.y;
      ld[ki * 33 + dq + 2] = v.z; ld[ki * 33 + dq + 3] = v.w;
    }
    __syncthreads();
    int dout = t >> 3, kq = (t & 7) * 4;
    size_t o = (size_t)(d0 + dout) * KK + k0 + kq;
    float4 e = *(const float4*)(ema_dw + o);
    float4 r;
    r.x = fmaf(e.x, DECAYF, ld[(kq + 0) * 33 + dout]) * inv / csn_s[kq + 0];
    r.y = fmaf(e.y, DECAYF, ld[(kq + 1) * 33 + dout]) * inv / csn_s[kq + 1];
    r.z = fmaf(e.z, DECAYF, ld[(kq + 2) * 33 + dout]) * inv / csn_s[kq + 2];
    r.w = fmaf(e.w, DECAYF, ld[(kq + 3) * 33 + dout]) * inv / csn_s[kq + 3];
    *(float4*)(out4 + o) = r;
  } else {
    int dout = t >> 3, kq = (t & 7) * 4;
    size_t o = (size_t)(d0 + dout) * KK + k0 + kq;
    *(float4*)(out4 + o) = *(const float4*)(emb + o);
  }
}

extern "C" void kernel_launch(void* const* d_in, const int* in_sizes, int n_in,
                              void* d_out, int out_size, void* d_ws, size_t ws_size,
                              hipStream_t stream) {
  (void)in_sizes; (void)n_in; (void)out_size; (void)ws_size;
  const float* x      = (const float*)d_in[0];
  const float* emb    = (const float*)d_in[1];
  const float* ema_cs = (const float*)d_in[2];
  const float* ema_dw = (const float*)d_in[3];
  const int*   counter = (const int*)d_in[4];
  const int*   train   = (const int*)d_in[5];

  float* out = (float*)d_out;
  float* outq    = out + O_Q;
  float* outloss = out + O_LOSS;
  float* outperp = out + O_PERP;
  float* outidx  = out + O_IDX;
  float* out4    = out + O_EMB;

  // workspace carve (bytes)
  char* W = (char*)d_ws;
  unsigned short* Ah   = (unsigned short*)(W);              //  8 MB fp16 x
  unsigned short* Eh   = (unsigned short*)(W + 8388608);    //  4 MB fp16 embT
  float* embT          = (float*)(W + 12582912);            //  8 MB fp32 embT
  float* part1         = (float*)(W + 20971520);            //  4 MB [kb][row]
  float* part2         = (float*)(W + 25165824);            //  4 MB [kb][row]
  int*   partidx       = (int*)(W + 29360128);              //  4 MB [kb][row]
  float* dwT           = part1;                             //  8 MB alias (dead after argmin2)
  unsigned long long* keysR = (unsigned long long*)(W + 33554432); // 128 KB
  float* esqp          = (float*)(W + 33685504);            // 256 KB [k*8+b]
  float* counts        = (float*)(W + 33947648);            // 32 KB
  float* loss_part     = (float*)(W + 33980416);            // 1 KB
  int*   listc         = (int*)(W + 33981440);              // 4 B
  int*   list          = (int*)(W + 33981444);              // 64 KB
  int*   idxw          = (int*)(W + 34046980);              // 64 KB

  // no memsets: all init fused into k_convert_xe
  k_convert_xe<<<6144, 256, 0, stream>>>(x, Ah, emb, Eh, embT, esqp, keysR, counts, loss_part, listc);
  k_dist_mfma<<<dim3(64, 128), 256, 0, stream>>>(Ah, Eh, esqp, part1, part2, partidx);
  k_argmin2<<<64, 256, 0, stream>>>(part1, part2, partidx, idxw, listc, list);
  k_rescore<<<dim3(256, 8), 256, 0, stream>>>(x, emb, listc, list, keysR);
  k_gather<<<4096, 256, 0, stream>>>(x, embT, idxw, keysR, train, outq, outidx, dwT, counts, loss_part);
  k_final<<<dim3(256, 8), 256, 0, stream>>>(dwT, ema_dw, emb, counts, ema_cs, loss_part, counter, train, out4, outloss, outperp);
}

// Round 15
// 336.003 us; speedup vs baseline: 1.2126x; 1.0482x over previous
//
#include <hip/hip_runtime.h>
#include <math.h>

#define DD 256
#define KK 8192
#define NN 16384
#define DECAYF 0.99f
#define EPSF 1e-5f
#define TAU 4e-3f

// output layout (floats)
#define O_Q    0
#define O_LOSS 4194304
#define O_PERP 4194305
#define O_IDX  4194306
#define O_EMB  4210690

typedef float f32x4 __attribute__((ext_vector_type(4)));
typedef _Float16 f16x8 __attribute__((ext_vector_type(8)));

__device__ __forceinline__ unsigned short f2h(float f) {
  union { _Float16 h; unsigned short u; } c;
  c.h = (_Float16)f;
  return c.u;
}

__device__ __forceinline__ void gll16(const void* g, void* l) {
  __builtin_amdgcn_global_load_lds((const __attribute__((address_space(1))) void*)g,
                                   (__attribute__((address_space(3))) void*)l, 16, 0, 0);
}

// DPP lane routing (VALU pipe, replaces ds_swizzle-based __shfl_xor).
#define DPPI(x, ctrl) __builtin_amdgcn_update_dpp((x), (x), (ctrl), 0xf, 0xf, true)
#define DPPF(x, ctrl) __int_as_float(__builtin_amdgcn_update_dpp(__float_as_int(x), __float_as_int(x), (ctrl), 0xf, 0xf, true))

// ------- fused convert + all workspace init (no memset nodes) -------
// bx<4096: x->fp16; bx<64 also init keysR; bx 64..95 zero counts;
// bx 96 zeroes listc. bx>=4096: emb transpose + esqp partials.
__global__ void k_convert_xe(const float* __restrict__ x, unsigned short* __restrict__ Ah,
                             const float* __restrict__ emb, unsigned short* __restrict__ Eh,
                             float* __restrict__ embT, float* __restrict__ esqp,
                             unsigned long long* __restrict__ keysR,
                             float* __restrict__ counts, int* __restrict__ listc) {
  __shared__ float ld[32 * 33];
  int bx = blockIdx.x;
  int t = threadIdx.x;
  if (bx < 4096) {
    int i = bx * 256 + t; // float4 index, 1048576 total
    float4 v = ((const float4*)x)[i];
    ushort4 h;
    h.x = f2h(v.x); h.y = f2h(v.y); h.z = f2h(v.z); h.w = f2h(v.w);
    ((ushort4*)Ah)[i] = h;
    if (bx < 64) {
      keysR[bx * 256 + t] = ~0ull;
    } else if (bx < 96) {
      counts[(bx - 64) * 256 + t] = 0.f;
    } else if (bx == 96) {
      if (t == 0) *listc = 0;
    }
    return;
  }
  int eb = bx - 4096;
  int k0 = (eb & 255) * 32, d0b = eb >> 8; // d0b in [0,8)
  {
    int din = t >> 3, kq = (t & 7) * 4;
    float4 v = *(const float4*)(emb + (size_t)(d0b * 32 + din) * KK + k0 + kq);
    ld[din * 33 + kq + 0] = v.x; ld[din * 33 + kq + 1] = v.y;
    ld[din * 33 + kq + 2] = v.z; ld[din * 33 + kq + 3] = v.w;
  }
  __syncthreads();
  int kout = t >> 3, dq = (t & 7) * 4;
  float f0 = ld[(dq + 0) * 33 + kout], f1 = ld[(dq + 1) * 33 + kout];
  float f2 = ld[(dq + 2) * 33 + kout], f3 = ld[(dq + 3) * 33 + kout];
  size_t o = (size_t)(k0 + kout) * DD + d0b * 32 + dq;
  float4 fv; fv.x = f0; fv.y = f1; fv.z = f2; fv.w = f3;
  *(float4*)(embT + o) = fv;
  ushort4 hv;
  hv.x = f2h(f0); hv.y = f2h(f1); hv.z = f2h(f2); hv.w = f2h(f3);
  *(ushort4*)(Eh + o) = hv;
  // esq partial: 8 threads (t&7) share kout; overwrite store (no init needed)
  float p = (f0 * f0 + f1 * f1) + (f2 * f2 + f3 * f3);
  p += __shfl_xor(p, 1, 64);
  p += __shfl_xor(p, 2, 64);
  p += __shfl_xor(p, 4, 64);
  if ((t & 7) == 0) esqp[(size_t)(k0 + kout) * 8 + d0b] = p;
}

// ---------------- MFMA distance screening (fp16 single GEMM) ----------------
// grid (64 kb, 128 nb); 4 waves; tile 128x128; A direct-to-reg, B via LDS.
// sEq pre-reduce in EPILOGUE (keeps main-loop VGPR at ~60).
// Partials stored [kb][row]: wave's 32 rows contiguous -> no write-amp.
__launch_bounds__(256, 2)
__global__ void k_dist_mfma(const unsigned short* __restrict__ Ah, const unsigned short* __restrict__ Bh,
                            const float* __restrict__ esqp,
                            float* __restrict__ part1, float* __restrict__ part2,
                            int* __restrict__ partidx) {
  __shared__ __align__(16) unsigned short sB[8192]; // 128 rows x 64 f16 (16 KB)
  __shared__ float sEq[128];

  const int tid = threadIdx.x;
  const int w = tid >> 6, lane = tid & 63;
  const int kb = blockIdx.x, nb = blockIdx.y;
  const int row0 = nb * 128, col0 = kb * 128;
  const int m = lane & 15, q = lane >> 4;

  // B staging: call s covers rows (w*4+s)*8 + (lane>>3); chunk (lane&7)^(r&7)
  size_t gB[4];
  int lbB[4];
  #pragma unroll
  for (int s = 0; s < 4; ++s) {
    int g = w * 4 + s;
    int r = g * 8 + (lane >> 3);
    int c = (lane & 7) ^ (r & 7);
    gB[s] = (size_t)(col0 + r) * DD + c * 8;
    lbB[s] = g * 512;
  }

  // A direct: lane (m,q) holds A[w*32 + i*16 + m][(kk*4+q)*8 ..+8] at d0=it*64
  const unsigned short* pA0 = Ah + (size_t)(row0 + w * 32 + m) * DD + q * 8;
  const unsigned short* pA1 = pA0 + 16 * DD;

  f32x4 acc[2][8];
  #pragma unroll
  for (int i = 0; i < 2; ++i)
    #pragma unroll
    for (int j = 0; j < 8; ++j) acc[i][j] = (f32x4)0.f;

  for (int it = 0; it < 4; ++it) {
    const int d0 = it * 64;
    __syncthreads();
    #pragma unroll
    for (int s = 0; s < 4; ++s) gll16(Bh + gB[s] + d0, sB + lbB[s]);
    f16x8 a[2][2];
    #pragma unroll
    for (int kk = 0; kk < 2; ++kk) {
      a[kk][0] = *(const f16x8*)(pA0 + d0 + kk * 32);
      a[kk][1] = *(const f16x8*)(pA1 + d0 + kk * 32);
    }
    __syncthreads();
    #pragma unroll
    for (int kk = 0; kk < 2; ++kk) {
      #pragma unroll
      for (int j = 0; j < 8; ++j) {
        int cn = j * 16 + m;
        int slot = (kk * 4 + q) ^ (cn & 7);
        f16x8 b = *(const f16x8*)(sB + cn * 64 + slot * 8);
        acc[0][j] = __builtin_amdgcn_mfma_f32_16x16x32_f16(a[kk][0], b, acc[0][j], 0, 0, 0);
        acc[1][j] = __builtin_amdgcn_mfma_f32_16x16x32_f16(a[kk][1], b, acc[1][j], 0, 0, 0);
      }
    }
  }

  // esq pre-reduce (EPILOGUE): thread t sums half (t&1) of col (t>>1); 4KB coalesced
  {
    int col = tid >> 1, half = tid & 1;
    const float4* ep = (const float4*)esqp + (size_t)(col0 + col) * 2 + half;
    float4 s = *ep;
    float p = (s.x + s.y) + (s.z + s.w);
    p += __shfl_xor(p, 1, 64); // partner lane, same col
    if (half == 0) sEq[col] = p;
  }
  __syncthreads();

  float eq[8];
  #pragma unroll
  for (int j = 0; j < 8; ++j) eq[j] = sEq[j * 16 + m];

  // argmin + 2nd-min; no index tie-break (exact ties -> gap 0 < TAU -> rescore)
  #define RSTAGE(CTRL) {                                  \
    float ov = DPPF(m1, CTRL);                            \
    int   oi = DPPI(bi, CTRL);                            \
    float o2 = DPPF(m2, CTRL);                            \
    m2 = fminf(fminf(m2, o2), fmaxf(m1, ov));             \
    bool p = ov < m1;                                     \
    m1 = fminf(m1, ov);                                   \
    bi = p ? oi : bi;                                     \
  }
  #pragma unroll
  for (int i = 0; i < 2; ++i) {
    #pragma unroll
    for (int reg = 0; reg < 4; ++reg) {
      float m1 = 3.402823466e+38f, m2 = 3.402823466e+38f;
      int bi = 0;
      #pragma unroll
      for (int j = 0; j < 8; ++j) {
        float dd = fmaf(-2.0f, acc[i][j][reg], eq[j]);
        bool p = dd < m1;
        m2 = fminf(m2, fmaxf(dd, m1));
        m1 = fminf(m1, dd);
        bi = p ? (col0 + j * 16 + m) : bi;
      }
      RSTAGE(0xB1)   // xor1  (quad_perm 1,0,3,2)
      RSTAGE(0x4E)   // xor2  (quad_perm 2,3,0,1)
      RSTAGE(0x141)  // xor7  (row_half_mirror)
      RSTAGE(0x140)  // xor15 (row_mirror)
      if (m == 0) {
        int prow = row0 + w * 32 + i * 16 + q * 4 + reg;
        int pidx = kb * NN + prow;  // [kb][row]: wave's 32 rows contiguous
        part1[pidx] = m1; part2[pidx] = m2; partidx[pidx] = bi;
      }
    }
  }
  #undef RSTAGE
}

// -------- per-row 2-min merge over 64 kb partials ([kb][row] layout) -------
// grid 64 x 256: thread owns one row; 64 coalesced loads per array, no
// shuffles. Zeroes dwT (=part1/part2 alias) element-by-element after read
// (same-thread read-then-zero: race-free across blocks).
__global__ void k_argmin2(float* __restrict__ part1, float* __restrict__ part2,
                          const int* __restrict__ partidx, int* __restrict__ idxw,
                          int* __restrict__ listc, int* __restrict__ list) {
  int row = blockIdx.x * 256 + threadIdx.x;
  float m1 = 3.402823466e+38f, m2 = 3.402823466e+38f;
  int bi = 0;
  for (int kb = 0; kb < 64; ++kb) {
    int f = kb * NN + row;
    float a1 = part1[f], a2 = part2[f];
    int ai = partidx[f];
    part1[f] = 0.f;  // dwT alias zeroing (own element only)
    part2[f] = 0.f;
    m2 = fminf(fminf(m2, a2), fmaxf(m1, a1));
    bool p = a1 < m1;
    m1 = fminf(m1, a1);
    bi = p ? ai : bi;
  }
  idxw[row] = bi;
  if (m2 - m1 < TAU) { int pos = atomicAdd(listc, 1); list[pos] = row; }
}

// ---------------- fp64 rescore of near-tie rows (parallel over rows) --------
// grid (256 k-slices, 8 row-stripes); early-exit BEFORE staging when empty.
__global__ void k_rescore(const float* __restrict__ x, const float* __restrict__ emb,
                          const int* __restrict__ listc, const int* __restrict__ list,
                          unsigned long long* __restrict__ keysR) {
  __shared__ float se[8192];
  __shared__ double red[256];
  const int t = threadIdx.x;
  const int k0 = blockIdx.x * 32;
  int cnt = *listc;
  if ((int)blockIdx.y >= cnt) return; // covers cnt==0; saves 32KB staging/block
  #pragma unroll
  for (int i = 0; i < 32; ++i) {
    int elem = i * 256 + t;
    int d = elem >> 5, c = elem & 31;
    se[d * 32 + c] = emb[(size_t)d * KK + k0 + c];
  }
  __syncthreads();
  const int c = t & 31, p = t >> 5;
  for (int li = blockIdx.y; li < cnt; li += gridDim.y) {
    int row = list[li];
    const float* xr = x + (size_t)row * DD;
    double acc = 0.0;
    #pragma unroll
    for (int j = 0; j < 32; ++j) {
      int d = p * 32 + j;
      double df = (double)xr[d] - (double)se[d * 32 + c];
      acc = fma(df, df, acc);
    }
    red[c * 8 + p] = acc;
    __syncthreads();
    if (t < 64) {
      unsigned long long key = ~0ull;
      if (t < 32) {
        double dist = 0.0;
        #pragma unroll
        for (int qq = 0; qq < 8; ++qq) dist += red[t * 8 + qq];
        key = ((unsigned long long)__double_as_longlong(dist) & ~0x1FFFull)
              | (unsigned long long)(k0 + t);
      }
      #pragma unroll
      for (int s = 1; s < 64; s <<= 1) {
        unsigned long long o = __shfl_xor(key, s, 64);
        if (o < key) key = o;
      }
      if (t == 0) atomicMin(&keysR[row], key);
    }
    __syncthreads();
  }
}

// ---------------- gather + outputs + scatter stats ----------------
// loss: non-atomic per-row partial into loss4k[n] (aliases dead partidx).
__global__ void k_gather(const float* __restrict__ x, const float* __restrict__ embT,
                         const int* __restrict__ idxw, const unsigned long long* __restrict__ keysR,
                         const int* __restrict__ train,
                         float* __restrict__ outq, float* __restrict__ outidx,
                         float* __restrict__ dwT, float* __restrict__ counts,
                         float* __restrict__ loss4k) {
  int w = threadIdx.x >> 6, l = threadIdx.x & 63;
  int n = blockIdx.x * 4 + w;
  unsigned long long kv = keysR[n];
  int k = (kv != ~0ull) ? (int)(kv & 0x1FFFull) : idxw[n];
  float4 xv = ((const float4*)(x + (size_t)n * DD))[l];
  float4 qv = ((const float4*)(embT + (size_t)k * DD))[l];
  int d = l * 4;

  ((float4*)(outq + (size_t)n * DD))[l] = qv; // x + (q - x) == q

  float e0 = qv.x - xv.x, e1 = qv.y - xv.y, e2 = qv.z - xv.z, e3 = qv.w - xv.w;
  float ls = (e0 * e0 + e1 * e1) + (e2 * e2 + e3 * e3);

  if (*train) {
    const float wdw = 1.0f - DECAYF;
    float* base = dwT + (size_t)k * DD + d;
    atomicAdd(base + 0, xv.x * wdw);
    atomicAdd(base + 1, xv.y * wdw);
    atomicAdd(base + 2, xv.z * wdw);
    atomicAdd(base + 3, xv.w * wdw);
  }

  #pragma unroll
  for (int s = 1; s < 64; s <<= 1) ls += __shfl_xor(ls, s, 64);
  if (l == 0) {
    loss4k[n] = ls;          // non-atomic per-row partial
    atomicAdd(&counts[k], 1.0f);
    outidx[n] = (float)k;
  }
}

// ------- finalize: grid (256,2), 4 d-tiles/block; nsum/csn computed ONCE ----
// block (0,0) additionally computes loss (from loss4k) + perplexity.
__global__ void k_final(const float* __restrict__ dwT, const float* __restrict__ ema_dw,
                        const float* __restrict__ emb, const float* __restrict__ counts,
                        const float* __restrict__ ema_cs, const float* __restrict__ loss4k,
                        const int* __restrict__ counter, const int* __restrict__ train,
                        float* __restrict__ out4, float* __restrict__ outloss,
                        float* __restrict__ outperp) {
  __shared__ float ld[32 * 33];
  __shared__ float s_red[4], s_l[4], s_e[4];
  __shared__ float csn_s[32];
  int t = threadIdx.x;
  int k0 = blockIdx.x * 32;
  int w = t >> 6, lane = t & 63;

  if (blockIdx.x == 0 && blockIdx.y == 0) {
    float lloc = 0.f, eloc = 0.f;
    for (int i = 0; i < 64; ++i) lloc += loss4k[t + i * 256];
    for (int i = 0; i < 32; ++i) {
      float cc = counts[t + i * 256];
      float pp = cc * (1.0f / 16384.0f);
      eloc += pp * logf(pp + 1e-10f);
    }
    #pragma unroll
    for (int s = 1; s < 64; s <<= 1) {
      lloc += __shfl_xor(lloc, s, 64);
      eloc += __shfl_xor(eloc, s, 64);
    }
    if (lane == 0) { s_l[w] = lloc; s_e[w] = eloc; }
    __syncthreads();
    if (t == 0) {
      outloss[0] = 0.25f * (((s_l[0] + s_l[1]) + (s_l[2] + s_l[3])) / 4194304.0f);
      outperp[0] = expf(-((s_e[0] + s_e[1]) + (s_e[2] + s_e[3])));
    }
  }

  if (*train) {
    float debias = 1.0f - powf(DECAYF, (float)(*counter + 1));
    float inv = 1.0f / debias;
    float nloc = 0.f;
    for (int i = 0; i < 32; ++i) {
      int k = t + i * 256;
      nloc += fmaf(counts[k], 1.0f - DECAYF, ema_cs[k] * DECAYF);
    }
    #pragma unroll
    for (int s = 1; s < 64; s <<= 1) nloc += __shfl_xor(nloc, s, 64);
    if (lane == 0) s_red[w] = nloc;
    __syncthreads();
    float nsum = ((s_red[0] + s_red[1]) + (s_red[2] + s_red[3])) * inv;
    if (t < 32) {
      int k = k0 + t;
      float a = fmaf(counts[k], 1.0f - DECAYF, ema_cs[k] * DECAYF) * inv;
      csn_s[t] = (a + EPSF) / (nsum + 8192.0f * EPSF) * nsum;
    }
    #pragma unroll
    for (int dt = 0; dt < 4; ++dt) {
      int d0 = blockIdx.y * 128 + dt * 32;
      {
        int ki = t >> 3, dq = (t & 7) * 4;
        float4 v = *(const float4*)(dwT + (size_t)(k0 + ki) * DD + d0 + dq);
        ld[ki * 33 + dq + 0] = v.x; ld[ki * 33 + dq + 1] = v.y;
        ld[ki * 33 + dq + 2] = v.z; ld[ki * 33 + dq + 3] = v.w;
      }
      __syncthreads();  // also publishes csn_s on dt==0
      int dout = t >> 3, kq = (t & 7) * 4;
      size_t o = (size_t)(d0 + dout) * KK + k0 + kq;
      float4 e = *(const float4*)(ema_dw + o);
      float4 r;
      r.x = fmaf(e.x, DECAYF, ld[(kq + 0) * 33 + dout]) * inv / csn_s[kq + 0];
      r.y = fmaf(e.y, DECAYF, ld[(kq + 1) * 33 + dout]) * inv / csn_s[kq + 1];
      r.z = fmaf(e.z, DECAYF, ld[(kq + 2) * 33 + dout]) * inv / csn_s[kq + 2];
      r.w = fmaf(e.w, DECAYF, ld[(kq + 3) * 33 + dout]) * inv / csn_s[kq + 3];
      *(float4*)(out4 + o) = r;
      __syncthreads();  // seal ld before next dt overwrites
    }
  } else {
    #pragma unroll
    for (int dt = 0; dt < 4; ++dt) {
      int d0 = blockIdx.y * 128 + dt * 32;
      int dout = t >> 3, kq = (t & 7) * 4;
      size_t o = (size_t)(d0 + dout) * KK + k0 + kq;
      *(float4*)(out4 + o) = *(const float4*)(emb + o);
    }
  }
}

extern "C" void kernel_launch(void* const* d_in, const int* in_sizes, int n_in,
                              void* d_out, int out_size, void* d_ws, size_t ws_size,
                              hipStream_t stream) {
  (void)in_sizes; (void)n_in; (void)out_size; (void)ws_size;
  const float* x      = (const float*)d_in[0];
  const float* emb    = (const float*)d_in[1];
  const float* ema_cs = (const float*)d_in[2];
  const float* ema_dw = (const float*)d_in[3];
  const int*   counter = (const int*)d_in[4];
  const int*   train   = (const int*)d_in[5];

  float* out = (float*)d_out;
  float* outq    = out + O_Q;
  float* outloss = out + O_LOSS;
  float* outperp = out + O_PERP;
  float* outidx  = out + O_IDX;
  float* out4    = out + O_EMB;

  // workspace carve (bytes)
  char* W = (char*)d_ws;
  unsigned short* Ah   = (unsigned short*)(W);              //  8 MB fp16 x
  unsigned short* Eh   = (unsigned short*)(W + 8388608);    //  4 MB fp16 embT
  float* embT          = (float*)(W + 12582912);            //  8 MB fp32 embT
  float* part1         = (float*)(W + 20971520);            //  4 MB [kb][row]
  float* part2         = (float*)(W + 25165824);            //  4 MB [kb][row]
  int*   partidx       = (int*)(W + 29360128);              //  4 MB [kb][row]
  float* dwT           = part1;                             //  8 MB alias (dead after argmin2)
  float* loss4k        = (float*)(W + 29360128);            // 64 KB alias (partidx dead after argmin2)
  unsigned long long* keysR = (unsigned long long*)(W + 33554432); // 128 KB
  float* esqp          = (float*)(W + 33685504);            // 256 KB [k*8+b]
  float* counts        = (float*)(W + 33947648);            // 32 KB
  int*   listc         = (int*)(W + 33981440);              // 4 B
  int*   list          = (int*)(W + 33981444);              // 64 KB
  int*   idxw          = (int*)(W + 34046980);              // 64 KB

  // no memsets: all init fused into k_convert_xe
  k_convert_xe<<<6144, 256, 0, stream>>>(x, Ah, emb, Eh, embT, esqp, keysR, counts, listc);
  k_dist_mfma<<<dim3(64, 128), 256, 0, stream>>>(Ah, Eh, esqp, part1, part2, partidx);
  k_argmin2<<<64, 256, 0, stream>>>(part1, part2, partidx, idxw, listc, list);
  k_rescore<<<dim3(256, 8), 256, 0, stream>>>(x, emb, listc, list, keysR);
  k_gather<<<4096, 256, 0, stream>>>(x, embT, idxw, keysR, train, outq, outidx, dwT, counts, loss4k);
  k_final<<<dim3(256, 2), 256, 0, stream>>>(dwT, ema_dw, emb, counts, ema_cs, loss4k, counter, train, out4, outloss, outperp);
}